// Round 9
// baseline (22998.318 us; speedup 1.0000x reference)
//
#include <hip/hip_runtime.h>
#include <hip/hip_fp16.h>
#include <math.h>

// R16: R15 with the macro-nesting compile error fixed (nested #define TAKE
//  inside BUILD_BLK was illegal). Build phase rewritten as a plain runtime
//  loop + lambda (one-time LDS-scratch work; registers still loaded via
//  compile-time-indexed SETVB/SETOB). Design identical to R15:
//  R11's proven fabric (128 WGs x 16 rows, 8 replicas, agent-scope tagged
//  b64 polls via __hip_atomic_* ONLY, single barrier, tid<16 publish) +
//  process-as-arrives MAC: sparse entries grouped per 128-word block
//  (CAPB=10 slots/block/lane, in-block mod-4 split); when __all lanes have
//  staged block b, its MAC group runs between masked load issues and tag
//  checks, hiding early blocks' MAC under in-flight poll rounds.
//  Padding entries: val 0.0f, offset = own block base (staged before the
//  group runs -> finite, contributes exactly 0).
//  Correctness chain (R7-proven) unchanged.

#define NWG        128
#define ROWS_PER_WG 16
#define T_STEPS    8192
#define WARMUP     100
#define RSIZE      2048
#define ISIZE      64
#define OUTCOLS    2112
#define MAXREP     8
#define REP_STRIDE_W 16384    // 64 KB / 4B between replica bases
#define CAPB       10         // sparse slots per lane per 128-word block

// ---- per-block register list machinery ----
#define EFOR(F,B) F(B,0) F(B,1) F(B,2) F(B,3) F(B,4) F(B,5) F(B,6) F(B,7) F(B,8) F(B,9)
#define PFOR(F,B) F(B,0) F(B,1) F(B,2) F(B,3) F(B,4)

#define DECLV(B,I) float v##B##_##I = 0.0f;
#define DECLO(B,P) unsigned o##B##_##P = 0u;
#define SETV(B,I)  v##B##_##I = sv[l * (4*CAPB) + (B)*CAPB + (I)];
#define SETO(B,P)  o##B##_##P = (unsigned)si[l * (4*CAPB) + (B)*CAPB + 2*(P)] \
                  | ((unsigned)si[l * (4*CAPB) + (B)*CAPB + 2*(P) + 1] << 16);
#define PINV(B,I)  asm volatile("" : "+v"(v##B##_##I));
#define PINO(B,P)  asm volatile("" : "+v"(o##B##_##P));

#define DECLVB(B) EFOR(DECLV,B)
#define DECLOB(B) PFOR(DECLO,B)
#define SETVB(B)  EFOR(SETV,B)
#define SETOB(B)  PFOR(SETO,B)
#define PINVB(B)  EFOR(PINV,B)
#define PINOB(B)  PFOR(PINO,B)

#define LDH(X) (*(const float*)(hsb + (X)))

#define MACGRP(B) { \
    const int cb = cms##B; \
    if (cb > 0) f0 = fmaf(v##B##_0, LDH(o##B##_0 & 0xFFFFu), f0); \
    if (cb > 1) f1 = fmaf(v##B##_1, LDH(o##B##_0 >> 16),     f1); \
    if (cb > 2) f0 = fmaf(v##B##_2, LDH(o##B##_1 & 0xFFFFu), f0); \
    if (cb > 3) f1 = fmaf(v##B##_3, LDH(o##B##_1 >> 16),     f1); \
    if (cb > 4) f0 = fmaf(v##B##_4, LDH(o##B##_2 & 0xFFFFu), f0); \
    if (cb > 5) f1 = fmaf(v##B##_5, LDH(o##B##_2 >> 16),     f1); \
    if (cb > 6) f0 = fmaf(v##B##_6, LDH(o##B##_3 & 0xFFFFu), f0); \
    if (cb > 7) f1 = fmaf(v##B##_7, LDH(o##B##_3 >> 16),     f1); \
    if (cb > 8) f0 = fmaf(v##B##_8, LDH(o##B##_4 & 0xFFFFu), f0); \
    if (cb > 9) f1 = fmaf(v##B##_9, LDH(o##B##_4 >> 16),     f1); }

static __device__ __forceinline__ float h16_to_f32(unsigned short u) {
    __half_raw hr; hr.x = u;
    return __half2float(__half(hr));
}
static __device__ __forceinline__ unsigned short f32_to_h16(float f) {
    __half_raw hr = __half_raw(__float2half_rn(f));
    return hr.x;
}

__global__ __launch_bounds__(256) void init_ws_kernel(unsigned* rep0, int nrep) {
    int t = blockIdx.x * blockDim.x + threadIdx.x;
    if (t < nrep * RSIZE) {
        int rep = t >> 11;          // RSIZE = 2048
        int idx = t & (RSIZE - 1);
        unsigned* b = rep0 + rep * REP_STRIDE_W;
        b[idx]         = 0u;           // buf0: (tag=0, h_0 = fp16 0)
        b[RSIZE + idx] = 0xFFFF0000u;  // buf1: tag 0xFFFF never matches
    }
}

__global__ __launch_bounds__(256) void xcopy_kernel(const float* __restrict__ x,
                                                    float* __restrict__ out) {
    int t = blockIdx.x * blockDim.x + threadIdx.x;
    if (t >= (T_STEPS - WARMUP) * ISIZE) return;
    int rowo = t >> 6;          // output row 0..8091
    int j    = t & 63;
    out[(size_t)rowo * OUTCOLS + RSIZE + j] = x[(size_t)(rowo + WARMUP) * ISIZE + j];
}

__global__ __launch_bounds__(256, 1) void esn_scan_kernel(
    const float* __restrict__ x,    // [8192][64]
    const float* __restrict__ Win,  // [2048][64]
    const float* __restrict__ Wh,   // [2048][2048]
    float* __restrict__ out,        // [8092][2112]
    unsigned* rep0,                 // replica 0 base; replicas at +r*REP_STRIDE_W
    int nrep, int repmask)          // nrep = pow2 in [1,8], repmask = nrep-1
{
    __shared__ __align__(16) float hs[RSIZE];     // staged h (word i at hs[i])
    __shared__ __align__(16) float part[64];      // part[r4*4 + w]
    __shared__ float sv[64 * 4 * CAPB];           // build scratch (per-wave phases)
    __shared__ unsigned short si[64 * 4 * CAPB];

    const int tid = threadIdx.x;      // 0..255
    const int wg  = blockIdx.x;       // 0..127
    const int w   = tid >> 6;         // wave 0..3 -> segment [512w, 512w+512)
    const int l   = tid & 63;         // lane
    const int r4  = l >> 2;           // row within WG served by this lane, 0..15
    const int c4  = l & 3;            // in-block parity class, 0..3
    const int row = wg * ROWS_PER_WG + r4;
    const int seg = w * 512;
    const char* hsb = (const char*)hs;

    // My poll replica (fixed per WG)
    const unsigned* myrep = rep0 + (wg & repmask) * REP_STRIDE_W;

    // ---- build per-block sparse (val, byteoff) register lists ----
    DECLVB(0) DECLVB(1) DECLVB(2) DECLVB(3)
    DECLOB(0) DECLOB(1) DECLOB(2) DECLOB(3)
    int myc[4] = {0, 0, 0, 0};
    const float* wrow = Wh + (size_t)row * RSIZE + seg;
    for (int ph = 0; ph < 4; ++ph) {
        if (w == ph) {
            // padding defaults: val 0, offset = own block base (always staged
            // before the block's group runs -> finite, contributes exactly 0)
            for (int b = 0; b < 4; ++b)
                for (int i = 0; i < CAPB; ++i) {
                    sv[l * (4*CAPB) + b * CAPB + i] = 0.0f;
                    si[l * (4*CAPB) + b * CAPB + i] = (unsigned short)((seg + b * 128) * 4);
                }
            for (int b = 0; b < 4; ++b) {
                int c = 0, c2 = 0;
                const float* wb = wrow + b * 128;
                auto take = [&](float val, int col) {
                    if (val != 0.0f) {
                        if ((c & 3) == c4 && c2 < CAPB) {
                            sv[l * (4*CAPB) + b * CAPB + c2] = val;
                            si[l * (4*CAPB) + b * CAPB + c2] =
                                (unsigned short)((seg + b * 128 + col) * 4);
                            ++c2;
                        }
                        ++c;
                    }
                };
                #pragma unroll 8
                for (int j = 0; j < 128; j += 4) {
                    const float4 t4 = *(const float4*)(wb + j);
                    take(t4.x, j); take(t4.y, j + 1); take(t4.z, j + 2); take(t4.w, j + 3);
                }
                myc[b] = c2;
            }
            SETVB(0) SETVB(1) SETVB(2) SETVB(3)
            SETOB(0) SETOB(1) SETOB(2) SETOB(3)
        }
        __syncthreads();
    }
    PINVB(0) PINVB(1) PINVB(2) PINVB(3)
    PINOB(0) PINOB(1) PINOB(2) PINOB(3)

    // wave-uniform per-block trip counts
    #define WMAX(CV, MV) int CV = MV; \
        _Pragma("unroll") \
        for (int d = 1; d < 64; d <<= 1) { const int o_ = __shfl_xor(CV, d); CV = o_ > CV ? o_ : CV; } \
        CV = __builtin_amdgcn_readfirstlane(CV);
    WMAX(cms0, myc[0]) WMAX(cms1, myc[1]) WMAX(cms2, myc[2]) WMAX(cms3, myc[3])
    #undef WMAX

    // pinned Win chunk: row, x-cols [16w + 4*c4, +4)
    float wix, wiy, wiz, wiw;
    { float4 t = *(const float4*)(Win + (size_t)row * ISIZE + w * 16 + c4 * 4);
      wix = t.x; wiy = t.y; wiz = t.z; wiw = t.w; }
    asm volatile("" : "+v"(wix), "+v"(wiy), "+v"(wiz), "+v"(wiw));

    float hcur = 0.0f;  // live only in lanes tid<16 (publish lanes)

    for (int k = 1; k <= T_STEPS; ++k) {
        // x chunk in flight during the poll
        const float4 xv = *(const float4*)(x + (size_t)(k - 1) * ISIZE + w * 16 + c4 * 4);

        // Win.x partial up front (accumulators live across the poll loop)
        float f0 = wix * xv.x + wiy * xv.y + wiz * xv.z + wiw * xv.w;
        float f1 = 0.0f;

        // ---- poll + process-as-arrives ----
        const unsigned* bp = myrep + (((k - 1) & 1) ? RSIZE : 0) + seg;
        const unsigned long long exp64 =
            ((unsigned long long)(unsigned)(k - 1) << 16) * 0x100000001ull; // both halves
        unsigned long long q[4];
        unsigned m = 0xFu;      // per-lane unmatched slots
        unsigned done = 0u;     // wave-uniform processed blocks
        for (;;) {
            // 1. issue masked loads (R11-proven transport form)
#pragma unroll
            for (int s = 0; s < 4; ++s) {
                if (m & (1u << s)) {
                    q[s] = __hip_atomic_load(
                        (const unsigned long long*)(bp + s * 128 + 2 * l),
                        __ATOMIC_RELAXED, __HIP_MEMORY_SCOPE_AGENT);
                }
            }
            // pin issue order: loads above, MAC below
            asm volatile("" ::: "memory");

            // 2. wave-uniform: run MAC groups whose block is fully staged
            if (!(done & 1u) && __all((m & 1u) == 0u)) { MACGRP(0) done |= 1u; }
            if (!(done & 2u) && __all((m & 2u) == 0u)) { MACGRP(1) done |= 2u; }
            if (!(done & 4u) && __all((m & 4u) == 0u)) { MACGRP(2) done |= 4u; }
            if (!(done & 8u) && __all((m & 8u) == 0u)) { MACGRP(3) done |= 8u; }
            if (done == 0xFu) break;

            // 3. check tags, stage matches (raw -> f32, R11 layout)
#pragma unroll
            for (int s = 0; s < 4; ++s) {
                if ((m & (1u << s)) &&
                    (q[s] & 0xFFFF0000FFFF0000ull) == exp64) {
                    float2 v;
                    v.x = h16_to_f32((unsigned short)(q[s] & 0xFFFFu));
                    v.y = h16_to_f32((unsigned short)((q[s] >> 32) & 0xFFFFu));
                    *(float2*)(hs + seg + s * 128 + 2 * l) = v;
                    m &= ~(1u << s);
                }
            }
        }

        // ---- reduce over the 4 c4 lanes (R11 verbatim) ----
        float p = f0 + f1;
        p += __shfl_xor(p, 1);
        p += __shfl_xor(p, 2);
        if (c4 == 0) part[r4 * 4 + w] = p;

        __syncthreads();   // the ONE barrier: guards the 64-float reduction

        // ---- publish lanes: combine, activate, publish to ALL replicas ----
        if (tid < 16) {
            const float4 ps = *(const float4*)(part + tid * 4);
            float y = ps.x + ps.y + ps.z + ps.w;
            float ax = fabsf(y);
            float e  = __expf(2.0f * ax);
            float t  = 1.0f - 2.0f / (e + 1.0f);
            t = copysignf(t, y);
            hcur = 0.99f * hcur + 0.01f * t;

            unsigned word = ((unsigned)k << 16) | (unsigned)f32_to_h16(hcur);
            const int slot = ((k & 1) ? RSIZE : 0) + wg * ROWS_PER_WG + tid;
#pragma unroll
            for (int rr = 0; rr < MAXREP; ++rr) {
                if (rr < nrep) {
                    __hip_atomic_store(rep0 + rr * REP_STRIDE_W + slot, word,
                                       __ATOMIC_RELAXED, __HIP_MEMORY_SCOPE_AGENT);
                }
            }
            if (k >= WARMUP + 1) {
                out[(size_t)(k - (WARMUP + 1)) * OUTCOLS + wg * ROWS_PER_WG + tid] = hcur;
            }
        }
        // no second barrier: hs segment is wave-private; part[] reuse protected
        // by the global publish->poll dependency chain (R7-proven).
    }
}

extern "C" void kernel_launch(void* const* d_in, const int* in_sizes, int n_in,
                              void* d_out, int out_size, void* d_ws, size_t ws_size,
                              hipStream_t stream) {
    const float* x   = (const float*)d_in[0];  // [8192*64]
    const float* Win = (const float*)d_in[1];  // [2048*64]
    const float* Wh  = (const float*)d_in[2];  // [2048*2048]
    float* out = (float*)d_out;                // [8092*2112]

    unsigned* rep0 = (unsigned*)d_ws;

    // nrep = largest power of two <= min(8, ws_size / 64KB)
    int nrep = MAXREP;
    while (nrep > 1 && (size_t)nrep * (REP_STRIDE_W * 4) > ws_size) nrep >>= 1;
    int repmask = nrep - 1;

    // init all replicas (ws is poisoned before every timed launch)
    {
        int n = nrep * RSIZE;
        init_ws_kernel<<<(n + 255) / 256, 256, 0, stream>>>(rep0, nrep);
    }

    // x-part of the output, independent of the recurrence
    {
        int n = (T_STEPS - WARMUP) * ISIZE;
        xcopy_kernel<<<(n + 255) / 256, 256, 0, stream>>>(x, out);
    }

    // the sequential scan: 128 persistent workgroups
    esn_scan_kernel<<<NWG, 256, 0, stream>>>(x, Win, Wh, out, rep0, nrep, repmask);
}

// Round 10
// 17321.588 us; speedup vs baseline: 1.3277x; 1.3277x over previous
//
#include <hip/hip_runtime.h>
#include <hip/hip_fp16.h>
#include <math.h>

// R17: restore R11 byte-identical (proven 17.36ms) after R16's refutation.
//  R16 post-mortem: process-as-arrives lengthened the spin-loop round period
//  (ballots + MAC + fence inside the poll loop) -> detection quantization
//  grew ~1650cy/step; FETCH dropped 442->406MB (fewer rounds) confirming the
//  mechanism. Rule (3x confirmed: R12/R13/R16): the spin loop must be
//  minimal; any work inside it multiplies into the handshake term.
//  Session scorecard inside the proven agent-scope fabric:
//   WIN : sparse-register Wh MAC (R11, 17.9->17.36ms)
//   FAIL: XCD-local L2 transport (R8-R10), hand-rolled CPol bits (R13/R14),
//         pipelined/streaming polls (R12/R13), process-as-arrives (R16),
//         bank-rotated gather order (R10).
//  R11 counters: step ~5080cy, ~4k of it handshake; WRITE 589MB / FETCH
//  442MB (~72/54 KB/step) = published h makes a full HBM round trip every
//  step (agent-scope coherence point effectively HBM-backed). Compute is
//  ~20% of the step. This restore re-anchors at the best known point.
// ---------------------------------------------------------------------------
// R11: R7's proven device-scope fabric (17.9ms) + sparse-register Wh MAC.
//  Byte-identical R7 communication structure (128 WGs x 16 rows, 8 replicas
//  64KB apart, agent-scope tagged b64 polls, single barrier, publish lanes
//  tid<16) with ONLY the Wh MAC replaced:
//   * dense 128-reg pinned chain (32 ds_read_b128/lane = ~1500cy LDS pipe)
//     -> sparse (val, byteoff) register lists (~13 avg / <=24 max random
//     ds_read_b32 gathers per lane, ~700-900cy incl. ~4-way conflicts).
//   * lane (r4, c4) takes the row-segment's compacted nonzeros with
//     compacted-index % 4 == c4; CAP 24/lane is guaranteed by the
//     R8-proven <=96 nonzeros per 512-col row-segment bound.
//   * zero-padded tail entries gather hs[0] * 0.0f — benign; wave-uniform
//     trip count cm (max over lanes) with uniform branches.
//  Staging: linear hs[2048], stage pair s at word seg + s*128 + 2l. Same-wave
//  ds ordering guards stage->gather (R7-proven). Numerics: fp32 sum over the
//  same terms, reordered; fp16-h quantization dominates (absmax 9.77e-4).

#define NWG        128
#define ROWS_PER_WG 16
#define T_STEPS    8192
#define WARMUP     100
#define RSIZE      2048
#define ISIZE      64
#define OUTCOLS    2112
#define MAXREP     8
#define REP_STRIDE_W 16384    // 64 KB / 4B between replica bases
#define CAPT       24         // sparse entries per lane (R8-proven bound /4)

#define REP24(F) \
  F(0) F(1) F(2) F(3) F(4) F(5) F(6) F(7) \
  F(8) F(9) F(10) F(11) F(12) F(13) F(14) F(15) \
  F(16) F(17) F(18) F(19) F(20) F(21) F(22) F(23)

#define REP12(F) \
  F(0) F(1) F(2) F(3) F(4) F(5) F(6) F(7) F(8) F(9) F(10) F(11)

#define PAIRS12(F) \
  F(0,0,1) F(1,2,3) F(2,4,5) F(3,6,7) F(4,8,9) F(5,10,11) \
  F(6,12,13) F(7,14,15) F(8,16,17) F(9,18,19) F(10,20,21) F(11,22,23)

#define DECLV(I) float v##I = 0.0f;
#define DECLO(I) unsigned op##I = 0u;
#define SETV(I)  v##I = sv[l * CAPT + (I)];
#define SETO(I)  op##I = (unsigned)si[l * CAPT + 2 * (I)] | ((unsigned)si[l * CAPT + 2 * (I) + 1] << 16);
#define PINV(I)  asm volatile("" : "+v"(v##I));
#define PINO(I)  asm volatile("" : "+v"(op##I));
#define MAC2(P, A, B) \
  if ((A) < cm) { p0 = fmaf(v##A, *(const float*)(hsb + (op##P & 0xFFFFu)), p0); } \
  if ((B) < cm) { p1 = fmaf(v##B, *(const float*)(hsb + (op##P >> 16)),     p1); }

static __device__ __forceinline__ float h16_to_f32(unsigned short u) {
    __half_raw hr; hr.x = u;
    return __half2float(__half(hr));
}
static __device__ __forceinline__ unsigned short f32_to_h16(float f) {
    __half_raw hr = __half_raw(__float2half_rn(f));
    return hr.x;
}

__global__ __launch_bounds__(256) void init_ws_kernel(unsigned* rep0, int nrep) {
    int t = blockIdx.x * blockDim.x + threadIdx.x;
    if (t < nrep * RSIZE) {
        int rep = t >> 11;          // RSIZE = 2048
        int idx = t & (RSIZE - 1);
        unsigned* b = rep0 + rep * REP_STRIDE_W;
        b[idx]         = 0u;           // buf0: (tag=0, h_0 = fp16 0)
        b[RSIZE + idx] = 0xFFFF0000u;  // buf1: tag 0xFFFF never matches
    }
}

__global__ __launch_bounds__(256) void xcopy_kernel(const float* __restrict__ x,
                                                    float* __restrict__ out) {
    int t = blockIdx.x * blockDim.x + threadIdx.x;
    if (t >= (T_STEPS - WARMUP) * ISIZE) return;
    int rowo = t >> 6;          // output row 0..8091
    int j    = t & 63;
    out[(size_t)rowo * OUTCOLS + RSIZE + j] = x[(size_t)(rowo + WARMUP) * ISIZE + j];
}

__global__ __launch_bounds__(256, 1) void esn_scan_kernel(
    const float* __restrict__ x,    // [8192][64]
    const float* __restrict__ Win,  // [2048][64]
    const float* __restrict__ Wh,   // [2048][2048]
    float* __restrict__ out,        // [8092][2112]
    unsigned* rep0,                 // replica 0 base; replicas at +r*REP_STRIDE_W
    int nrep, int repmask)          // nrep = pow2 in [1,8], repmask = nrep-1
{
    __shared__ __align__(16) float hs[RSIZE];     // staged h (wave w: [512w,512w+512))
    __shared__ float part[64];                    // part[r4*4 + w]
    __shared__ float sv[64 * CAPT];               // build scratch (per-wave phases)
    __shared__ unsigned short si[64 * CAPT];

    const int tid = threadIdx.x;      // 0..255
    const int wg  = blockIdx.x;       // 0..127
    const int w   = tid >> 6;         // wave 0..3 -> h segment [512w, 512w+512)
    const int l   = tid & 63;         // lane
    const int r4  = l >> 2;           // row within WG served by this lane, 0..15
    const int c4  = l & 3;            // parity class of compacted nonzeros, 0..3
    const int row = wg * ROWS_PER_WG + r4;
    const int seg = w * 512;
    const char* hsb = (const char*)hs;

    // My poll replica (fixed per WG)
    const unsigned* myrep = rep0 + (wg & repmask) * REP_STRIDE_W;

    // ---- build sparse (val, byteoff) register lists, wave-staggered ----
    int cnt = 0;
    REP24(DECLV)
    REP12(DECLO)
    const float* wrow = Wh + (size_t)row * RSIZE + seg;
    for (int ph = 0; ph < 4; ++ph) {
        if (w == ph) {
            for (int i = 0; i < CAPT; ++i) { sv[l * CAPT + i] = 0.0f; si[l * CAPT + i] = 0; }
            int c = 0, c2 = 0;
            #pragma unroll 8
            for (int j = 0; j < 512; j += 4) {
                const float4 t4 = *(const float4*)(wrow + j);
                #define TAKE(VAL, COMP) \
                    if ((VAL) != 0.0f) { \
                        if ((c & 3) == c4 && c2 < CAPT) { \
                            sv[l * CAPT + c2] = (VAL); \
                            si[l * CAPT + c2] = (unsigned short)((seg + j + (COMP)) * 4); \
                            ++c2; \
                        } \
                        ++c; \
                    }
                TAKE(t4.x, 0) TAKE(t4.y, 1) TAKE(t4.z, 2) TAKE(t4.w, 3)
                #undef TAKE
            }
            cnt = c2;
            REP24(SETV)
            REP12(SETO)
        }
        __syncthreads();
    }
    REP24(PINV)
    REP12(PINO)

    // wave-uniform trip count (zero-padded entries are benign)
    int cm = cnt;
    #pragma unroll
    for (int d = 1; d < 64; d <<= 1) { const int o = __shfl_xor(cm, d); cm = o > cm ? o : cm; }
    cm = __builtin_amdgcn_readfirstlane(cm);

    // pinned Win chunk (R7 verbatim): row, x-cols [16w + 4*c4, +4)
    float wix, wiy, wiz, wiw;
    { float4 t = *(const float4*)(Win + (size_t)row * ISIZE + w * 16 + c4 * 4);
      wix = t.x; wiy = t.y; wiz = t.z; wiw = t.w; }
    asm volatile("" : "+v"(wix), "+v"(wiy), "+v"(wiz), "+v"(wiw));

    float hcur = 0.0f;  // live only in lanes tid<16 (publish lanes)

    for (int k = 1; k <= T_STEPS; ++k) {
        // x chunk in flight during the poll
        const float4 xv = *(const float4*)(x + (size_t)(k - 1) * ISIZE + w * 16 + c4 * 4);

        // ---- poll my replica's segment: 4 coalesced b64 loads (R7 verbatim) ----
        const unsigned* bp = myrep + (((k - 1) & 1) ? RSIZE : 0) + seg;
        const unsigned long long exp64 =
            ((unsigned long long)(unsigned)(k - 1) << 16) * 0x100000001ull; // both halves
        unsigned long long q[4];
        unsigned m = 0xFu;
        while (m) {
#pragma unroll
            for (int s = 0; s < 4; ++s) {
                if (m & (1u << s)) {
                    q[s] = __hip_atomic_load(
                        (const unsigned long long*)(bp + s * 128 + 2 * l),
                        __ATOMIC_RELAXED, __HIP_MEMORY_SCOPE_AGENT);
                }
            }
#pragma unroll
            for (int s = 0; s < 4; ++s) {
                if ((m & (1u << s)) &&
                    (q[s] & 0xFFFF0000FFFF0000ull) == exp64) {
                    m &= ~(1u << s);
                }
            }
        }

        // ---- stage segment -> LDS (linear f32); same-wave ds ordering ----
#pragma unroll
        for (int s = 0; s < 4; ++s) {
            float2* d = (float2*)(hs + seg + s * 128 + 2 * l);
            float2 v;
            v.x = h16_to_f32((unsigned short)(q[s] & 0xFFFFu));
            v.y = h16_to_f32((unsigned short)((q[s] >> 32) & 0xFFFFu));
            *d = v;
        }

        // ---- Win.x partial while the stage drains ----
        float p0 = wix * xv.x + wiy * xv.y + wiz * xv.z + wiw * xv.w;
        float p1 = 0.0f;

        // ---- sparse MAC over my row's parity-class entries in this segment ----
        PAIRS12(MAC2)

        // reduce over the 4 c4 lanes (R7 verbatim)
        float p = p0 + p1;
        p += __shfl_xor(p, 1);
        p += __shfl_xor(p, 2);
        if (c4 == 0) part[r4 * 4 + w] = p;

        __syncthreads();   // the ONE barrier: guards the 64-float reduction

        // ---- publish lanes: combine, activate, publish to ALL replicas ----
        if (tid < 16) {
            const float4 ps = *(const float4*)(part + tid * 4);
            float y = ps.x + ps.y + ps.z + ps.w;
            float ax = fabsf(y);
            float e  = __expf(2.0f * ax);
            float t  = 1.0f - 2.0f / (e + 1.0f);
            t = copysignf(t, y);
            hcur = 0.99f * hcur + 0.01f * t;

            unsigned word = ((unsigned)k << 16) | (unsigned)f32_to_h16(hcur);
            const int slot = ((k & 1) ? RSIZE : 0) + wg * ROWS_PER_WG + tid;
#pragma unroll
            for (int rr = 0; rr < MAXREP; ++rr) {
                if (rr < nrep) {
                    __hip_atomic_store(rep0 + rr * REP_STRIDE_W + slot, word,
                                       __ATOMIC_RELAXED, __HIP_MEMORY_SCOPE_AGENT);
                }
            }
            if (k >= WARMUP + 1) {
                out[(size_t)(k - (WARMUP + 1)) * OUTCOLS + wg * ROWS_PER_WG + tid] = hcur;
            }
        }
        // no second barrier: hs segment is wave-private; part[] reuse protected
        // by the global publish->poll dependency chain (R7-proven).
    }
}

extern "C" void kernel_launch(void* const* d_in, const int* in_sizes, int n_in,
                              void* d_out, int out_size, void* d_ws, size_t ws_size,
                              hipStream_t stream) {
    const float* x   = (const float*)d_in[0];  // [8192*64]
    const float* Win = (const float*)d_in[1];  // [2048*64]
    const float* Wh  = (const float*)d_in[2];  // [2048*2048]
    float* out = (float*)d_out;                // [8092*2112]

    unsigned* rep0 = (unsigned*)d_ws;

    // nrep = largest power of two <= min(8, ws_size / 64KB)
    int nrep = MAXREP;
    while (nrep > 1 && (size_t)nrep * (REP_STRIDE_W * 4) > ws_size) nrep >>= 1;
    int repmask = nrep - 1;

    // init all replicas (ws is poisoned 0xAA before every timed launch)
    {
        int n = nrep * RSIZE;
        init_ws_kernel<<<(n + 255) / 256, 256, 0, stream>>>(rep0, nrep);
    }

    // x-part of the output, independent of the recurrence
    {
        int n = (T_STEPS - WARMUP) * ISIZE;
        xcopy_kernel<<<(n + 255) / 256, 256, 0, stream>>>(x, out);
    }

    // the sequential scan: 128 persistent workgroups
    esn_scan_kernel<<<NWG, 256, 0, stream>>>(x, Win, Wh, out, rep0, nrep, repmask);
}